// Round 3
// baseline (1796.049 us; speedup 1.0000x reference)
//
#include <hip/hip_runtime.h>

#define NVEC 65536   // B*H*W = 64*32*32
#define KC   1024
#define DD   64
#define SPLIT 8
#define KPB  (KC / SPLIT)   // 128 codes per block

// d_out layout (f32): [0]=loss, [1..4194305)=z_q (B,D,H,W), [4194305]=perplexity, [4194306..)=idx
#define OUT_ZQ   1
#define OUT_PPL  4194305
#define OUT_IDX  4194306

// ws layout (bytes)
#define WS_KEYS  0                        // u64[NVEC]   = 524288
#define WS_HIST  524288                   // int[KC]     = 4096
#define WS_SUMSQ 528384                   // double      = 8
#define WS_SE    528392                   // float[KC]   = 4096

// prep_emb: se[k] = np.sum(emb**2, axis=1), numpy pairwise order (8 stride-8
// accumulators, tree combine), f32.
__global__ __launch_bounds__(256) void prep_emb(const float* __restrict__ emb,
                                                float* __restrict__ se) {
    const int k = blockIdx.x * 256 + threadIdx.x;
    const float* er = emb + (size_t)k * 64;
    float r[8];
    #pragma unroll
    for (int c = 0; c < 64; ++c) {
        float v = er[c];
        float s = __fmul_rn(v, v);
        if (c < 8) r[c] = s;
        else       r[c & 7] = __fadd_rn(r[c & 7], s);
    }
    se[k] = __fadd_rn(__fadd_rn(__fadd_rn(r[0], r[1]), __fadd_rn(r[2], r[3])),
                      __fadd_rn(__fadd_rn(r[4], r[5]), __fadd_rn(r[6], r[7])));
}

// dist: thread <-> one n. z-row (64 floats) lives in VGPRs; emb rows are
// wave-uniform reads (scalarize to s_load); argmin is thread-local via a
// packed (monotone-f32 << 10 | k) u64 key; one atomicMin per thread merges
// the SPLIT k-ranges. Arithmetic is bit-identical to the verified round-2
// BLAS-order emulation: sequential __fmaf_rn chain over c, then
// fl(fl(sz+se) - fl(2*acc)).
__global__ __launch_bounds__(256, 4) void dist_kernel(const float* __restrict__ z,
                                                      const float* __restrict__ emb,
                                                      const float* __restrict__ se,
                                                      unsigned long long* __restrict__ keys) {
    const int tid = threadIdx.x;
    const int n   = blockIdx.x * 256 + tid;
    const int b   = n >> 10;
    const int hw  = n & 1023;
    const float* zp = z + (size_t)b * 65536 + hw;   // stride 1024 over c; lane-coalesced per c

    float zd[64];
    #pragma unroll
    for (int c = 0; c < 64; ++c) zd[c] = zp[(size_t)c * 1024];

    // sz[n] = np.sum(zf**2) pairwise emulation (same as verified round 2)
    float r[8];
    #pragma unroll
    for (int c = 0; c < 64; ++c) {
        float s = __fmul_rn(zd[c], zd[c]);
        if (c < 8) r[c] = s;
        else       r[c & 7] = __fadd_rn(r[c & 7], s);
    }
    const float szn = __fadd_rn(__fadd_rn(__fadd_rn(r[0], r[1]), __fadd_rn(r[2], r[3])),
                                __fadd_rn(__fadd_rn(r[4], r[5]), __fadd_rn(r[6], r[7])));

    const int k0 = blockIdx.y * KPB;
    unsigned long long bestkey = 0xFFFFFFFFFFFFFFFFULL;

    for (int kk = 0; kk < KPB; kk += 4) {
        const int k = k0 + kk;
        const float* __restrict__ e0 = emb + (size_t)(k + 0) * 64;
        const float* __restrict__ e1 = emb + (size_t)(k + 1) * 64;
        const float* __restrict__ e2 = emb + (size_t)(k + 2) * 64;
        const float* __restrict__ e3 = emb + (size_t)(k + 3) * 64;
        float a0 = 0.f, a1 = 0.f, a2 = 0.f, a3 = 0.f;
        #pragma unroll
        for (int c = 0; c < 64; ++c) {
            a0 = __fmaf_rn(zd[c], e0[c], a0);
            a1 = __fmaf_rn(zd[c], e1[c], a1);
            a2 = __fmaf_rn(zd[c], e2[c], a2);
            a3 = __fmaf_rn(zd[c], e3[c], a3);
        }
        const float accs[4] = {a0, a1, a2, a3};
        #pragma unroll
        for (int j = 0; j < 4; ++j) {
            float d = __fsub_rn(__fadd_rn(szn, se[k + j]),
                                __fmul_rn(2.0f, accs[j]));
            unsigned m = __float_as_uint(d);
            m ^= ((int)m < 0) ? 0xFFFFFFFFu : 0x80000000u;
            unsigned long long key =
                ((unsigned long long)m << 10) | (unsigned)(k + j);
            bestkey = (key < bestkey) ? key : bestkey;   // first-index tie-break
        }
    }
    atomicMin(&keys[n], bestkey);
}

__global__ __launch_bounds__(256) void epilogue_kernel(const float* __restrict__ z,
                                                       const float* __restrict__ emb,
                                                       const unsigned long long* __restrict__ keys,
                                                       float* __restrict__ out,
                                                       int* __restrict__ hist,
                                                       double* __restrict__ sumsq) {
    __shared__ double red[256];
    const int tid = threadIdx.x;
    const int n   = blockIdx.x * 256 + tid;
    const int b   = n >> 10;
    const int hw  = n & 1023;
    const int idx = (int)(keys[n] & 1023ULL);

    out[OUT_IDX + n] = (float)idx;
    atomicAdd(&hist[idx], 1);

    const float* zp = z   + (size_t)b * 65536 + hw;
    float*       op = out + OUT_ZQ + (size_t)b * 65536 + hw;
    const float* er = emb + (size_t)idx * DD;
    double s = 0.0;
    #pragma unroll
    for (int c = 0; c < DD; ++c) {
        float zv   = zp[(size_t)c * 1024];
        float ev   = er[c];
        float diff = ev - zv;                  // z_q - z
        op[(size_t)c * 1024] = zv + diff;      // straight-through: z + sg(z_q - z)
        s = fma((double)diff, (double)diff, s);
    }
    red[tid] = s;
    __syncthreads();
    for (int off = 128; off > 0; off >>= 1) {
        if (tid < off) red[tid] += red[tid + off];
        __syncthreads();
    }
    if (tid == 0) atomicAdd(sumsq, red[0]);
}

__global__ __launch_bounds__(256) void final_kernel(const int* __restrict__ hist,
                                                    const double* __restrict__ sumsq,
                                                    float* __restrict__ out) {
    __shared__ double red[256];
    const int tid = threadIdx.x;
    double s = 0.0;
    #pragma unroll
    for (int j = 0; j < 4; ++j) {
        int   kk = j * 256 + tid;
        float em = (float)hist[kk] * (1.0f / 65536.0f);
        float t  = em * logf(em + 1e-10f);
        s += (double)t;
    }
    red[tid] = s;
    __syncthreads();
    for (int off = 128; off > 0; off >>= 1) {
        if (tid < off) red[tid] += red[tid + off];
        __syncthreads();
    }
    if (tid == 0) {
        out[OUT_PPL] = expf(-(float)red[0]);
        out[0]       = 1.25f * (float)(sumsq[0] / 4194304.0);
    }
}

extern "C" void kernel_launch(void* const* d_in, const int* in_sizes, int n_in,
                              void* d_out, int out_size, void* d_ws, size_t ws_size,
                              hipStream_t stream) {
    const float* z   = (const float*)d_in[0];
    const float* emb = (const float*)d_in[1];
    float* out = (float*)d_out;
    char*  ws  = (char*)d_ws;

    unsigned long long* keys  = (unsigned long long*)(ws + WS_KEYS);
    int*                hist  = (int*)(ws + WS_HIST);
    double*             sumsq = (double*)(ws + WS_SUMSQ);
    float*              se    = (float*)(ws + WS_SE);

    hipMemsetAsync(keys, 0xFF, (size_t)NVEC * 8, stream);
    hipMemsetAsync(hist, 0, (size_t)KC * 4 + 8, stream);  // hist + sumsq contiguous

    prep_emb<<<KC / 256, 256, 0, stream>>>(emb, se);
    dist_kernel<<<dim3(NVEC / 256, SPLIT), 256, 0, stream>>>(z, emb, se, keys);
    epilogue_kernel<<<NVEC / 256, 256, 0, stream>>>(z, emb, keys, out, hist, sumsq);
    final_kernel<<<1, 256, 0, stream>>>(hist, sumsq, out);
}

// Round 4
// 178.103 us; speedup vs baseline: 10.0843x; 10.0843x over previous
//
#include <hip/hip_runtime.h>

#define NVEC 65536   // B*H*W = 64*32*32
#define KC   1024
#define DD   64
#define SPLIT 4
#define KPB  (KC / SPLIT)   // 256 codes per block
#define KTILE 64            // emb rows staged in LDS per barrier

// d_out layout (f32): [0]=loss, [1..4194305)=z_q (B,D,H,W), [4194305]=perplexity, [4194306..)=idx
#define OUT_ZQ   1
#define OUT_PPL  4194305
#define OUT_IDX  4194306

// ws layout (bytes)
#define WS_KEYS  0                        // u64[NVEC]   = 524288
#define WS_HIST  524288                   // int[KC]     = 4096
#define WS_SUMSQ 528384                   // double      = 8
#define WS_SE    528392                   // float[KC]   = 4096

// prep_emb: se[k] = np.sum(emb**2, axis=1), numpy pairwise order (8 stride-8
// accumulators, tree combine), f32.
__global__ __launch_bounds__(256) void prep_emb(const float* __restrict__ emb,
                                                float* __restrict__ se) {
    const int k = blockIdx.x * 256 + threadIdx.x;
    const float* er = emb + (size_t)k * 64;
    float r[8];
    #pragma unroll
    for (int c = 0; c < 64; ++c) {
        float v = er[c];
        float s = __fmul_rn(v, v);
        if (c < 8) r[c] = s;
        else       r[c & 7] = __fadd_rn(r[c & 7], s);
    }
    se[k] = __fadd_rn(__fadd_rn(__fadd_rn(r[0], r[1]), __fadd_rn(r[2], r[3])),
                      __fadd_rn(__fadd_rn(r[4], r[5]), __fadd_rn(r[6], r[7])));
}

// dist: thread <-> one n. z-row (64 floats) pinned in VGPRs (waves_per_eu(4,4)
// -> 128-VGPR budget, no spill). emb tiles staged in LDS; inner reads are
// wave-uniform -> broadcast ds_read_b128. Argmin thread-local (d < dbest,
// ascending k = first-index tie-break), one atomicMin per thread merges the
// SPLIT k-ranges. Arithmetic bit-identical to the verified round-2/3 chain.
__global__ __launch_bounds__(256)
__attribute__((amdgpu_waves_per_eu(4, 4)))
void dist_kernel(const float* __restrict__ z,
                 const float* __restrict__ emb,
                 const float* __restrict__ se,
                 unsigned long long* __restrict__ keys) {
    __shared__ float lds_e[KTILE * DD];   // 16 KB
    __shared__ float lds_se[KPB];         // 1 KB
    const int tid = threadIdx.x;
    const int n   = blockIdx.x * 256 + tid;
    const int b   = n >> 10;
    const int hw  = n & 1023;
    const float* zp = z + (size_t)b * 65536 + hw;   // stride 1024 over c; lane-coalesced per c

    float zd[64];
    #pragma unroll
    for (int c = 0; c < 64; ++c) zd[c] = zp[(size_t)c * 1024];

    // sz[n] = np.sum(zf**2) pairwise emulation (verified)
    float r[8];
    #pragma unroll
    for (int c = 0; c < 64; ++c) {
        float s = __fmul_rn(zd[c], zd[c]);
        if (c < 8) r[c] = s;
        else       r[c & 7] = __fadd_rn(r[c & 7], s);
    }
    const float szn = __fadd_rn(__fadd_rn(__fadd_rn(r[0], r[1]), __fadd_rn(r[2], r[3])),
                                __fadd_rn(__fadd_rn(r[4], r[5]), __fadd_rn(r[6], r[7])));

    const int k0 = blockIdx.y * KPB;
    // stage this block's se slice once (KPB floats = KPB/4 float4 loads)
    if (tid < KPB / 4) ((float4*)lds_se)[tid] = ((const float4*)(se + k0))[tid];

    float dbest = 3.4e38f;
    int   kbest = 0;

    for (int t = 0; t < KPB / KTILE; ++t) {
        __syncthreads();
        // stage 64x64 f32 emb tile: 1024 float4, 256 threads x 4 (coalesced)
        const float4* src = (const float4*)(emb + (size_t)(k0 + t * KTILE) * DD);
        float4*       dst = (float4*)lds_e;
        #pragma unroll
        for (int j = 0; j < 4; ++j) dst[j * 256 + tid] = src[j * 256 + tid];
        __syncthreads();

        for (int kk = 0; kk < KTILE; kk += 4) {
            const float* e0 = lds_e + (kk + 0) * 64;   // wave-uniform -> broadcast
            const float* e1 = lds_e + (kk + 1) * 64;
            const float* e2 = lds_e + (kk + 2) * 64;
            const float* e3 = lds_e + (kk + 3) * 64;
            float a0 = 0.f, a1 = 0.f, a2 = 0.f, a3 = 0.f;
            #pragma unroll
            for (int c = 0; c < 64; ++c) {
                a0 = __fmaf_rn(zd[c], e0[c], a0);
                a1 = __fmaf_rn(zd[c], e1[c], a1);
                a2 = __fmaf_rn(zd[c], e2[c], a2);
                a3 = __fmaf_rn(zd[c], e3[c], a3);
            }
            const float4 seq = *(const float4*)&lds_se[t * KTILE + kk];
            const float accs[4] = {a0, a1, a2, a3};
            const float ses[4]  = {seq.x, seq.y, seq.z, seq.w};
            #pragma unroll
            for (int j = 0; j < 4; ++j) {
                float d = __fsub_rn(__fadd_rn(szn, ses[j]),
                                    __fmul_rn(2.0f, accs[j]));
                if (d < dbest) { dbest = d; kbest = k0 + t * KTILE + kk + j; }
            }
        }
    }

    unsigned m = __float_as_uint(dbest);
    m ^= ((int)m < 0) ? 0xFFFFFFFFu : 0x80000000u;
    atomicMin(&keys[n], ((unsigned long long)m << 10) | (unsigned)kbest);
}

__global__ __launch_bounds__(256) void epilogue_kernel(const float* __restrict__ z,
                                                       const float* __restrict__ emb,
                                                       const unsigned long long* __restrict__ keys,
                                                       float* __restrict__ out,
                                                       int* __restrict__ hist,
                                                       double* __restrict__ sumsq) {
    __shared__ double red[256];
    const int tid = threadIdx.x;
    const int n   = blockIdx.x * 256 + tid;
    const int b   = n >> 10;
    const int hw  = n & 1023;
    const int idx = (int)(keys[n] & 1023ULL);

    out[OUT_IDX + n] = (float)idx;
    atomicAdd(&hist[idx], 1);

    const float* zp = z   + (size_t)b * 65536 + hw;
    float*       op = out + OUT_ZQ + (size_t)b * 65536 + hw;
    const float* er = emb + (size_t)idx * DD;
    double s = 0.0;
    #pragma unroll
    for (int c = 0; c < DD; ++c) {
        float zv   = zp[(size_t)c * 1024];
        float ev   = er[c];
        float diff = ev - zv;                  // z_q - z
        op[(size_t)c * 1024] = zv + diff;      // straight-through: z + sg(z_q - z)
        s = fma((double)diff, (double)diff, s);
    }
    red[tid] = s;
    __syncthreads();
    for (int off = 128; off > 0; off >>= 1) {
        if (tid < off) red[tid] += red[tid + off];
        __syncthreads();
    }
    if (tid == 0) atomicAdd(sumsq, red[0]);
}

__global__ __launch_bounds__(256) void final_kernel(const int* __restrict__ hist,
                                                    const double* __restrict__ sumsq,
                                                    float* __restrict__ out) {
    __shared__ double red[256];
    const int tid = threadIdx.x;
    double s = 0.0;
    #pragma unroll
    for (int j = 0; j < 4; ++j) {
        int   kk = j * 256 + tid;
        float em = (float)hist[kk] * (1.0f / 65536.0f);
        float t  = em * logf(em + 1e-10f);
        s += (double)t;
    }
    red[tid] = s;
    __syncthreads();
    for (int off = 128; off > 0; off >>= 1) {
        if (tid < off) red[tid] += red[tid + off];
        __syncthreads();
    }
    if (tid == 0) {
        out[OUT_PPL] = expf(-(float)red[0]);
        out[0]       = 1.25f * (float)(sumsq[0] / 4194304.0);
    }
}

extern "C" void kernel_launch(void* const* d_in, const int* in_sizes, int n_in,
                              void* d_out, int out_size, void* d_ws, size_t ws_size,
                              hipStream_t stream) {
    const float* z   = (const float*)d_in[0];
    const float* emb = (const float*)d_in[1];
    float* out = (float*)d_out;
    char*  ws  = (char*)d_ws;

    unsigned long long* keys  = (unsigned long long*)(ws + WS_KEYS);
    int*                hist  = (int*)(ws + WS_HIST);
    double*             sumsq = (double*)(ws + WS_SUMSQ);
    float*              se    = (float*)(ws + WS_SE);

    hipMemsetAsync(keys, 0xFF, (size_t)NVEC * 8, stream);
    hipMemsetAsync(hist, 0, (size_t)KC * 4 + 8, stream);  // hist + sumsq contiguous

    prep_emb<<<KC / 256, 256, 0, stream>>>(emb, se);
    dist_kernel<<<dim3(NVEC / 256, SPLIT), 256, 0, stream>>>(z, emb, se, keys);
    epilogue_kernel<<<NVEC / 256, 256, 0, stream>>>(z, emb, keys, out, hist, sumsq);
    final_kernel<<<1, 256, 0, stream>>>(hist, sumsq, out);
}

// Round 5
// 146.321 us; speedup vs baseline: 12.2747x; 1.2172x over previous
//
#include <hip/hip_runtime.h>

#define NVEC 65536   // B*H*W = 64*32*32
#define KC   1024
#define DD   64
#define NTILE 64     // n per block
#define KTILE 128    // k per LDS tile
#define ETS  136     // padded et stride in floats (16B-aligned rows, 2-way max on stage)

// d_out layout (f32): [0]=loss, [1..4194305)=z_q (B,D,H,W), [4194305]=perplexity, [4194306..)=idx
#define OUT_ZQ   1
#define OUT_PPL  4194305
#define OUT_IDX  4194306

// ws layout (bytes)
#define WS_KEYS  0                        // u64[NVEC]   = 524288
#define WS_HIST  524288                   // int[KC]     = 4096
#define WS_SUMSQ 528384                   // double      = 8
#define WS_SE    528392                   // float[KC]   = 4096

// prep_emb: se[k] = np.sum(emb**2, axis=1), numpy pairwise order (8 stride-8
// accumulators, tree combine), f32. (verified bit-exact)
__global__ __launch_bounds__(256) void prep_emb(const float* __restrict__ emb,
                                                float* __restrict__ se) {
    const int k = blockIdx.x * 256 + threadIdx.x;
    const float* er = emb + (size_t)k * 64;
    float r[8];
    #pragma unroll
    for (int c = 0; c < 64; ++c) {
        float v = er[c];
        float s = __fmul_rn(v, v);
        if (c < 8) r[c] = s;
        else       r[c & 7] = __fadd_rn(r[c & 7], s);
    }
    se[k] = __fadd_rn(__fadd_rn(__fadd_rn(r[0], r[1]), __fadd_rn(r[2], r[3])),
                      __fadd_rn(__fadd_rn(r[4], r[5]), __fadd_rn(r[6], r[7])));
}

// dist: register-tiled GEMM-with-argmin. Block = 64 n x all 1024 k.
// zt[c][n] (z is already c-major: no transpose), et[c][k] (staged transpose).
// Thread (tn=tid&15, tk=tid>>4) owns 4n x 8k accumulators.
// Arithmetic bit-identical to the verified chain: per (n,k) sequential
// __fmaf_rn over c=0..63, then fl(fl(sz+se) - fl(2*acc)); k ascending,
// strict < => numpy first-index tie-break.
__global__ __launch_bounds__(256)
void dist_kernel(const float* __restrict__ z,
                 const float* __restrict__ emb,
                 const float* __restrict__ se,
                 unsigned long long* __restrict__ keys) {
    __shared__ float zt[64][64];                 // 16 KB
    __shared__ float et[64][ETS];                // 34.8 KB
    __shared__ float lds_sz[64];
    __shared__ unsigned long long red[64];

    const int tid = threadIdx.x;
    const int tn  = tid & 15;      // n-group: 4 n each
    const int tk  = tid >> 4;      // k-group: 8 k each (within 128-k tile)
    const int n0  = blockIdx.x * NTILE;
    const int b   = n0 >> 10;
    const int hw0 = n0 & 1023;     // 64-aligned

    // ---- stage zt[c][nl]: global is [b][c][hw], hw is n-contiguous ----
    {
        const float* zbase = z + (size_t)b * 65536 + hw0;
        #pragma unroll
        for (int j = 0; j < 4; ++j) {
            int idx = tid + j * 256;
            int c   = idx >> 4;
            int nl4 = (idx & 15) * 4;
            float4 v = *(const float4*)(zbase + (size_t)c * 1024 + nl4);
            *(float4*)&zt[c][nl4] = v;
        }
        if (tid < 64) red[tid] = 0xFFFFFFFFFFFFFFFFULL;
    }
    __syncthreads();

    // ---- sz[n] from staged zt, exact numpy pairwise order ----
    if (tid < 64) {
        float r[8];
        #pragma unroll
        for (int c = 0; c < 64; ++c) {
            float v = zt[c][tid];
            float s = __fmul_rn(v, v);
            if (c < 8) r[c] = s;
            else       r[c & 7] = __fadd_rn(r[c & 7], s);
        }
        lds_sz[tid] = __fadd_rn(
            __fadd_rn(__fadd_rn(r[0], r[1]), __fadd_rn(r[2], r[3])),
            __fadd_rn(__fadd_rn(r[4], r[5]), __fadd_rn(r[6], r[7])));
    }
    // visibility of lds_sz guaranteed by the barrier after et staging below

    float dbest[4] = {3.4e38f, 3.4e38f, 3.4e38f, 3.4e38f};
    int   kbest[4] = {0, 0, 0, 0};

    for (int t = 0; t < KC / KTILE; ++t) {
        const int k0 = t * KTILE;

        // ---- stage et[c][k] (transpose of emb[k][c]) ----
        {
            int k  = tid >> 1;                 // 0..127
            int cq = tid & 1;                  // 0..1
            const float* erow = emb + (size_t)(k0 + k) * 64;
            #pragma unroll
            for (int q = 0; q < 8; ++q) {
                int cb = cq * 4 + q * 8;
                float4 v = *(const float4*)(erow + cb);
                et[cb + 0][k] = v.x;
                et[cb + 1][k] = v.y;
                et[cb + 2][k] = v.z;
                et[cb + 3][k] = v.w;
            }
        }
        __syncthreads();

        float acc[4][8];
        #pragma unroll
        for (int i = 0; i < 4; ++i)
            #pragma unroll
            for (int j = 0; j < 8; ++j) acc[i][j] = 0.0f;

        #pragma unroll 4
        for (int c = 0; c < 64; ++c) {
            const float4 zv  = *(const float4*)&zt[c][tn * 4];
            const float4 ev0 = *(const float4*)&et[c][tk * 8];
            const float4 ev1 = *(const float4*)&et[c][tk * 8 + 4];
            const float zr[4] = {zv.x, zv.y, zv.z, zv.w};
            const float er[8] = {ev0.x, ev0.y, ev0.z, ev0.w,
                                 ev1.x, ev1.y, ev1.z, ev1.w};
            #pragma unroll
            for (int i = 0; i < 4; ++i)
                #pragma unroll
                for (int j = 0; j < 8; ++j)
                    acc[i][j] = __fmaf_rn(zr[i], er[j], acc[i][j]);
        }

        const float4 sev0 = *(const float4*)(se + k0 + tk * 8);
        const float4 sev1 = *(const float4*)(se + k0 + tk * 8 + 4);
        const float ses[8] = {sev0.x, sev0.y, sev0.z, sev0.w,
                              sev1.x, sev1.y, sev1.z, sev1.w};
        const float4 szv = *(const float4*)&lds_sz[tn * 4];
        const float szs[4] = {szv.x, szv.y, szv.z, szv.w};

        #pragma unroll
        for (int i = 0; i < 4; ++i)
            #pragma unroll
            for (int j = 0; j < 8; ++j) {
                float d = __fsub_rn(__fadd_rn(szs[i], ses[j]),
                                    __fmul_rn(2.0f, acc[i][j]));
                if (d < dbest[i]) { dbest[i] = d; kbest[i] = k0 + tk * 8 + j; }
            }
        __syncthreads();   // protect et before next stage overwrites
    }

    #pragma unroll
    for (int i = 0; i < 4; ++i) {
        unsigned m = __float_as_uint(dbest[i]);
        m ^= ((int)m < 0) ? 0xFFFFFFFFu : 0x80000000u;
        atomicMin(&red[tn * 4 + i],
                  ((unsigned long long)m << 10) | (unsigned)kbest[i]);
    }
    __syncthreads();
    if (tid < 64) keys[n0 + tid] = red[tid];
}

__global__ __launch_bounds__(256) void epilogue_kernel(const float* __restrict__ z,
                                                       const float* __restrict__ emb,
                                                       const unsigned long long* __restrict__ keys,
                                                       float* __restrict__ out,
                                                       int* __restrict__ hist,
                                                       double* __restrict__ sumsq) {
    __shared__ double red[256];
    const int tid = threadIdx.x;
    const int n   = blockIdx.x * 256 + tid;
    const int b   = n >> 10;
    const int hw  = n & 1023;
    const int idx = (int)(keys[n] & 1023ULL);

    out[OUT_IDX + n] = (float)idx;
    atomicAdd(&hist[idx], 1);

    const float* zp = z   + (size_t)b * 65536 + hw;
    float*       op = out + OUT_ZQ + (size_t)b * 65536 + hw;
    const float* er = emb + (size_t)idx * DD;
    double s = 0.0;
    #pragma unroll
    for (int c = 0; c < DD; ++c) {
        float zv   = zp[(size_t)c * 1024];
        float ev   = er[c];
        float diff = ev - zv;                  // z_q - z
        op[(size_t)c * 1024] = zv + diff;      // straight-through: z + sg(z_q - z)
        s = fma((double)diff, (double)diff, s);
    }
    red[tid] = s;
    __syncthreads();
    for (int off = 128; off > 0; off >>= 1) {
        if (tid < off) red[tid] += red[tid + off];
        __syncthreads();
    }
    if (tid == 0) atomicAdd(sumsq, red[0]);
}

__global__ __launch_bounds__(256) void final_kernel(const int* __restrict__ hist,
                                                    const double* __restrict__ sumsq,
                                                    float* __restrict__ out) {
    __shared__ double red[256];
    const int tid = threadIdx.x;
    double s = 0.0;
    #pragma unroll
    for (int j = 0; j < 4; ++j) {
        int   kk = j * 256 + tid;
        float em = (float)hist[kk] * (1.0f / 65536.0f);
        float t  = em * logf(em + 1e-10f);
        s += (double)t;
    }
    red[tid] = s;
    __syncthreads();
    for (int off = 128; off > 0; off >>= 1) {
        if (tid < off) red[tid] += red[tid + off];
        __syncthreads();
    }
    if (tid == 0) {
        out[OUT_PPL] = expf(-(float)red[0]);
        out[0]       = 1.25f * (float)(sumsq[0] / 4194304.0);
    }
}

extern "C" void kernel_launch(void* const* d_in, const int* in_sizes, int n_in,
                              void* d_out, int out_size, void* d_ws, size_t ws_size,
                              hipStream_t stream) {
    const float* z   = (const float*)d_in[0];
    const float* emb = (const float*)d_in[1];
    float* out = (float*)d_out;
    char*  ws  = (char*)d_ws;

    unsigned long long* keys  = (unsigned long long*)(ws + WS_KEYS);
    int*                hist  = (int*)(ws + WS_HIST);
    double*             sumsq = (double*)(ws + WS_SUMSQ);
    float*              se    = (float*)(ws + WS_SE);

    hipMemsetAsync(hist, 0, (size_t)KC * 4 + 8, stream);  // hist + sumsq contiguous

    prep_emb<<<KC / 256, 256, 0, stream>>>(emb, se);
    dist_kernel<<<NVEC / NTILE, 256, 0, stream>>>(z, emb, se, keys);
    epilogue_kernel<<<NVEC / 256, 256, 0, stream>>>(z, emb, keys, out, hist, sumsq);
    final_kernel<<<1, 256, 0, stream>>>(hist, sumsq, out);
}